// Round 5
// baseline (48.368 us; speedup 1.0000x reference)
//
#include <hip/hip_runtime.h>
#include <hip/hip_bf16.h>

#define B_ 64
#define N_ 576
#define D_ 384
#define K_ 4096
#define CPB 16              // chunks (blocks) per batch
#define RPB (N_ / CPB)      // 36 rows per chunk

// Fused single kernel, fence-free producer->consumer:
//   Phase 1 (all 1024 blocks): project rows -> y, where y is written with
//     RELAXED AGENT-scope atomic stores (global_store sc0 sc1: write-through
//     to L3, the device coherence point). No cache flush needed.
//   Signal: s_waitcnt vmcnt(0) (stores complete at L3) + __syncthreads, then
//     tid0 does a relaxed agent-scope atomicAdd on ctr[b].
//   Phase 2 (the 16th arriver per batch; never spins): gathers that batch's
//     4096 pairs reading y via relaxed agent-scope atomic loads (bypass
//     L1/L2, served from L3). Fully unrolled 16-pair/thread loop for ILP.
// R3 lesson: per-block __threadfence (L2 writeback) cost ~92us; this design
// has zero fences.
__global__ __launch_bounds__(256) void partvit_fused(const float* __restrict__ z,
                                                     const int* __restrict__ idx,
                                                     const float* __restrict__ W,
                                                     const float* __restrict__ bias,
                                                     float* __restrict__ out,
                                                     float* __restrict__ idx_out,
                                                     unsigned long long* __restrict__ y,
                                                     unsigned int* __restrict__ ctr) {
    const int g = blockIdx.x;
    const int b = g >> 4;     // batch
    const int c = g & 15;     // chunk within batch
    const int tid = threadIdx.x;
    const int hw = tid >> 5;  // half-wave 0..7
    const int s  = tid & 31;  // column-chunk owner
    const int c4 = s * 3;

    // Touch this block's slice of idx (2KB) so it lands in L3 before the
    // winner's gather needs it (L3 is memory-side, shared across XCDs).
    {
        const int2 pf = reinterpret_cast<const int2*>(idx)[b * K_ + c * 256 + tid];
        asm volatile("" :: "v"(pf.x), "v"(pf.y));
    }

    const float4* Wq = reinterpret_cast<const float4*>(W);
    const float4* zq = reinterpret_cast<const float4*>(z);
    const int row0 = b * N_ + c * RPB;

    // W[t][f] at t*768+f. float4 view: W0[:384]=Wq[0..95], W0[384:]=Wq[96..191],
    //                                  W1[:384]=Wq[192..287], W1[384:]=Wq[288..383]
    for (int r = hw; r < RPB; r += 8) {
        const int row = row0 + r;
        const float4* zr = zq + (size_t)row * 96 + c4;
        const float4 v0 = zr[0], v1 = zr[1], v2 = zr[2];

        float a0, a1, a2, a3;
        {
            const float4 wa = Wq[c4],       wb = Wq[c4 + 1],     wc = Wq[c4 + 2];
            a0 = v0.x*wa.x + v0.y*wa.y + v0.z*wa.z + v0.w*wa.w
               + v1.x*wb.x + v1.y*wb.y + v1.z*wb.z + v1.w*wb.w
               + v2.x*wc.x + v2.y*wc.y + v2.z*wc.z + v2.w*wc.w;
        }
        {
            const float4 wa = Wq[192+c4],   wb = Wq[192+c4+1],   wc = Wq[192+c4+2];
            a1 = v0.x*wa.x + v0.y*wa.y + v0.z*wa.z + v0.w*wa.w
               + v1.x*wb.x + v1.y*wb.y + v1.z*wb.z + v1.w*wb.w
               + v2.x*wc.x + v2.y*wc.y + v2.z*wc.z + v2.w*wc.w;
        }
        {
            const float4 wa = Wq[96+c4],    wb = Wq[96+c4+1],    wc = Wq[96+c4+2];
            a2 = v0.x*wa.x + v0.y*wa.y + v0.z*wa.z + v0.w*wa.w
               + v1.x*wb.x + v1.y*wb.y + v1.z*wb.z + v1.w*wb.w
               + v2.x*wc.x + v2.y*wc.y + v2.z*wc.z + v2.w*wc.w;
        }
        {
            const float4 wa = Wq[288+c4],   wb = Wq[288+c4+1],   wc = Wq[288+c4+2];
            a3 = v0.x*wa.x + v0.y*wa.y + v0.z*wa.z + v0.w*wa.w
               + v1.x*wb.x + v1.y*wb.y + v1.z*wb.z + v1.w*wb.w
               + v2.x*wc.x + v2.y*wc.y + v2.z*wc.z + v2.w*wc.w;
        }

#pragma unroll
        for (int off = 16; off > 0; off >>= 1) {
            a0 += __shfl_xor(a0, off);
            a1 += __shfl_xor(a1, off);
            a2 += __shfl_xor(a2, off);
            a3 += __shfl_xor(a3, off);
        }
        if (s == 0) {
            union { float2 f; unsigned long long u; } u0, u1;
            u0.f = make_float2(a0, a1);
            u1.f = make_float2(a2, a3);
            // write-through to L3 (device coherence point), no fence needed
            __hip_atomic_store(&y[(size_t)row * 2 + 0], u0.u,
                               __ATOMIC_RELAXED, __HIP_MEMORY_SCOPE_AGENT);
            __hip_atomic_store(&y[(size_t)row * 2 + 1], u1.u,
                               __ATOMIC_RELAXED, __HIP_MEMORY_SCOPE_AGENT);
        }
    }

    // All y stores for this block complete at the coherence point.
    asm volatile("s_waitcnt vmcnt(0)" ::: "memory");
    __syncthreads();
    __shared__ unsigned int old_s;
    if (tid == 0) {
        old_s = __hip_atomic_fetch_add(&ctr[b], 1u,
                                       __ATOMIC_RELAXED, __HIP_MEMORY_SCOPE_AGENT);
    }
    __syncthreads();
    if (old_s != CPB - 1) return;   // last arriver gathers; nobody spins

    // ---- Phase 2: gather batch b (16 pairs per thread, fully unrolled) ----
    const float b0 = bias[0], b1 = bias[1];
    const unsigned long long* yb = y + (size_t)b * N_ * 2;
    const int base = b * K_;
#pragma unroll
    for (int i = 0; i < K_ / 256; ++i) {
        const int t = base + i * 256 + tid;
        const int2 p = reinterpret_cast<const int2*>(idx)[t];
        union { float2 f; unsigned long long u; } q0, q1;
        q0.u = __hip_atomic_load(&yb[(size_t)p.x * 2 + 0],
                                 __ATOMIC_RELAXED, __HIP_MEMORY_SCOPE_AGENT);
        q1.u = __hip_atomic_load(&yb[(size_t)p.y * 2 + 1],
                                 __ATOMIC_RELAXED, __HIP_MEMORY_SCOPE_AGENT);
        float2 o;
        o.x = q0.f.x + q1.f.x + b0;
        o.y = q0.f.y + q1.f.y + b1;
        reinterpret_cast<float2*>(out)[t] = o;
        float2 io;
        io.x = (float)p.x;
        io.y = (float)p.y;
        reinterpret_cast<float2*>(idx_out)[t] = io;
    }
}

extern "C" void kernel_launch(void* const* d_in, const int* in_sizes, int n_in,
                              void* d_out, int out_size, void* d_ws, size_t ws_size,
                              hipStream_t stream) {
    const float* z    = (const float*)d_in[0];
    const int*   idx  = (const int*)d_in[1];
    const float* W    = (const float*)d_in[2];
    const float* bias = (const float*)d_in[3];

    float* out     = (float*)d_out;                        // [B,K,2] floats
    float* idx_out = (float*)d_out + (size_t)B_ * K_ * 2;  // indices as float
    unsigned long long* y = (unsigned long long*)d_ws;     // [B*N][2] = 576 KB
    unsigned int* ctr = (unsigned int*)((char*)d_ws + (1 << 20));  // 64 counters

    // Counters must be 0 each call (ws poisoned once, never re-poisoned).
    hipMemsetAsync(ctr, 0, B_ * sizeof(unsigned int), stream);

    // 16 blocks per batch x 64 batches = 1024 blocks (4/CU co-resident)
    partvit_fused<<<B_ * CPB, 256, 0, stream>>>(z, idx, W, bias,
                                                out, idx_out, y, ctr);
}